// Round 1
// baseline (815.317 us; speedup 1.0000x reference)
//
#include <hip/hip_runtime.h>

// Problem constants (match reference setup_inputs()).
constexpr int N_USERS = 50000;
constexpr int N_ITEMS = 20000;
constexpr int RATES   = 5;
constexpr int F       = 64;   // IN_FEAT == HID_FEAT

// Workspace layout (floats):
//   ssum_u : N_USERS*RATES*F = 16,000,000
//   ssum_v : N_ITEMS*RATES*F =  6,400,000
//   cnt_u  : N_USERS*RATES   =    250,000
//   cnt_v  : N_ITEMS*RATES   =    100,000
constexpr long SSUM_U_FLOATS = (long)N_USERS * RATES * F;
constexpr long SSUM_V_FLOATS = (long)N_ITEMS * RATES * F;
constexpr long CNT_U_FLOATS  = (long)N_USERS * RATES;
constexpr long CNT_V_FLOATS  = (long)N_ITEMS * RATES;
constexpr long WS_FLOATS     = SSUM_U_FLOATS + SSUM_V_FLOATS + CNT_U_FLOATS + CNT_V_FLOATS;
constexpr long OUT_FLOATS    = (long)(N_USERS + N_ITEMS) * F;

// ---------------------------------------------------------------------------
// Kernel 1: zero workspace + output (both are poisoned 0xAA before each call)
// ---------------------------------------------------------------------------
__global__ void zero_kernel(float4* __restrict__ ws, long n_ws4,
                            float4* __restrict__ out, long n_out4) {
    long i = (long)blockIdx.x * blockDim.x + threadIdx.x;
    long stride = (long)gridDim.x * blockDim.x;
    float4 z = make_float4(0.f, 0.f, 0.f, 0.f);
    for (long k = i; k < n_ws4; k += stride)  ws[k]  = z;
    for (long k = i; k < n_out4; k += stride) out[k] = z;
}

// ---------------------------------------------------------------------------
// Kernel 2: edge scatter. One wave (64 lanes) per edge; lane = feature index.
// Both directions handled by the same wave (x_item row -> user segs,
// x_user row -> item segs). Counts bumped once per edge from lane 0.
// ---------------------------------------------------------------------------
__global__ void scatter_kernel(const int* __restrict__ u_s,
                               const int* __restrict__ v_s,
                               const int* __restrict__ rate,
                               const float* __restrict__ x_user,
                               const float* __restrict__ x_item,
                               float* __restrict__ ssum_u,
                               float* __restrict__ ssum_v,
                               float* __restrict__ cnt_u,
                               float* __restrict__ cnt_v,
                               int n_edges) {
    long gid  = (long)blockIdx.x * blockDim.x + threadIdx.x;
    int  e    = (int)(gid >> 6);
    int  lane = (int)(gid & 63);
    if (e >= n_edges) return;

    int u = u_s[e];
    int v = v_s[e];
    int r = rate[e];

    float xi = x_item[(long)v * F + lane];
    atomicAdd(ssum_u + ((long)u * RATES + r) * F + lane, xi);

    float xu = x_user[(long)u * F + lane];
    atomicAdd(ssum_v + ((long)v * RATES + r) * F + lane, xu);

    if (lane == 0) {
        atomicAdd(cnt_u + (long)u * RATES + r, 1.0f);
        atomicAdd(cnt_v + (long)v * RATES + r, 1.0f);
    }
}

// ---------------------------------------------------------------------------
// Kernel 3: per-node matmul. out[n,h] = sum_r inv_c(n,r) * sum_d ssum[n,r,d]*W[r,d,h]
// One wave per tile of T nodes; lane = output feature h. W loads are
// coalesced (stride-1 in lane); ssum/cnt loads are wave-uniform.
// ---------------------------------------------------------------------------
constexpr int T = 8;  // nodes per wave

__global__ void matmul_kernel(const float* __restrict__ ssum,
                              const float* __restrict__ cnt,
                              const float* __restrict__ W,   // [RATES][F][F]
                              float* __restrict__ out,
                              int n_nodes) {
    int wave = (int)(((long)blockIdx.x * blockDim.x + threadIdx.x) >> 6);
    int lane = threadIdx.x & 63;
    int node0 = wave * T;
    if (node0 >= n_nodes) return;

    float acc[T];
#pragma unroll
    for (int t = 0; t < T; t++) acc[t] = 0.f;

    for (int r = 0; r < RATES; r++) {
        float partial[T];
#pragma unroll
        for (int t = 0; t < T; t++) partial[t] = 0.f;

        for (int d0 = 0; d0 < F; d0 += 8) {
            float w[8];
#pragma unroll
            for (int j = 0; j < 8; j++)
                w[j] = W[((long)r * F + d0 + j) * F + lane];
#pragma unroll
            for (int t = 0; t < T; t++) {
                const float* s = ssum + (((long)(node0 + t) * RATES + r) * F) + d0;
#pragma unroll
                for (int j = 0; j < 8; j++)
                    partial[t] += s[j] * w[j];
            }
        }
#pragma unroll
        for (int t = 0; t < T; t++) {
            float c = cnt[(long)(node0 + t) * RATES + r];
            float inv = 1.0f / fmaxf(c, 1.0f);
            acc[t] += partial[t] * inv;
        }
    }
#pragma unroll
    for (int t = 0; t < T; t++)
        out[(long)(node0 + t) * F + lane] = acc[t];
}

// ---------------------------------------------------------------------------
extern "C" void kernel_launch(void* const* d_in, const int* in_sizes, int n_in,
                              void* d_out, int out_size, void* d_ws, size_t ws_size,
                              hipStream_t stream) {
    const int*   u_s    = (const int*)d_in[0];
    const int*   v_s    = (const int*)d_in[1];
    const int*   rate   = (const int*)d_in[2];
    const float* x_user = (const float*)d_in[3];
    const float* x_item = (const float*)d_in[4];
    const float* W      = (const float*)d_in[5];
    float* out = (float*)d_out;

    int n_edges = in_sizes[0];

    float* ws     = (float*)d_ws;
    float* ssum_u = ws;
    float* ssum_v = ssum_u + SSUM_U_FLOATS;
    float* cnt_u  = ssum_v + SSUM_V_FLOATS;
    float* cnt_v  = cnt_u + CNT_U_FLOATS;

    // Zero ws + out every call (harness re-poisons both with 0xAA).
    long n_ws4  = WS_FLOATS / 4;   // 22,750,000 / 4 = 5,687,500
    long n_out4 = OUT_FLOATS / 4;  // 4,480,000 / 4  = 1,120,000
    if ((size_t)WS_FLOATS * sizeof(float) > ws_size) {
        // Workspace too small: zero output only (visible failure, no OOB).
        zero_kernel<<<2048, 256, 0, stream>>>((float4*)d_ws, 0, (float4*)out, n_out4);
        return;
    }
    zero_kernel<<<2048, 256, 0, stream>>>((float4*)d_ws, n_ws4, (float4*)out, n_out4);

    // Scatter: one wave per edge.
    {
        long total_threads = (long)n_edges * 64;
        int  blocks = (int)((total_threads + 255) / 256);
        scatter_kernel<<<blocks, 256, 0, stream>>>(u_s, v_s, rate, x_user, x_item,
                                                   ssum_u, ssum_v, cnt_u, cnt_v, n_edges);
    }

    // Segment matmuls.
    {
        float* h_u = out;
        float* h_v = out + (long)N_USERS * F;
        int waves_u  = (N_USERS + T - 1) / T;          // 6250
        int blocks_u = (waves_u + 3) / 4;              // 4 waves per 256-thread block
        matmul_kernel<<<blocks_u, 256, 0, stream>>>(ssum_u, cnt_u, W, h_u, N_USERS);
        int waves_v  = (N_ITEMS + T - 1) / T;          // 2500
        int blocks_v = (waves_v + 3) / 4;
        matmul_kernel<<<blocks_v, 256, 0, stream>>>(ssum_v, cnt_v, W, h_v, N_ITEMS);
    }
}

// Round 2
// 697.328 us; speedup vs baseline: 1.1692x; 1.1692x over previous
//
#include <hip/hip_runtime.h>

// Problem constants (match reference setup_inputs()).
constexpr int N_USERS = 50000;
constexpr int N_ITEMS = 20000;
constexpr int RATES   = 5;
constexpr int F       = 64;   // IN_FEAT == HID_FEAT

constexpr int SEG_U     = N_USERS * RATES;          // 250,000
constexpr int SEG_V     = N_ITEMS * RATES;          // 100,000
constexpr int NS_TOTAL  = SEG_U + SEG_V;            // 350,000
constexpr long OUT_FLOATS = (long)(N_USERS + N_ITEMS) * F;

// Scan geometry.
constexpr int SCAN_BS    = 256;
constexpr int SCAN_ELEMS = 8;
constexpr int SCAN_CHUNK = SCAN_BS * SCAN_ELEMS;    // 2048
constexpr int SCAN_NB    = (NS_TOTAL + SCAN_CHUNK - 1) / SCAN_CHUNK;  // 171 (<=256)

// ---------------------------------------------------------------------------
// zero a range of ints (counts table); also used to zero out on ws-fallback
// ---------------------------------------------------------------------------
__global__ void zero_ints(int* __restrict__ p, long n) {
    long i = (long)blockIdx.x * blockDim.x + threadIdx.x;
    long stride = (long)gridDim.x * blockDim.x;
    for (long k = i; k < n; k += stride) p[k] = 0;
}

// ---------------------------------------------------------------------------
// histogram: counts per (dst node, rating) segment, both directions
// ---------------------------------------------------------------------------
__global__ void hist_kernel(const int* __restrict__ u_s,
                            const int* __restrict__ v_s,
                            const int* __restrict__ rate,
                            int* __restrict__ cnt, int n_edges) {
    int e = blockIdx.x * blockDim.x + threadIdx.x;
    if (e >= n_edges) return;
    int r = rate[e];
    atomicAdd(&cnt[u_s[e] * RATES + r], 1);
    atomicAdd(&cnt[SEG_U + v_s[e] * RATES + r], 1);
}

// ---------------------------------------------------------------------------
// 3-step exclusive scan over NS_TOTAL counts
// ---------------------------------------------------------------------------
__global__ void scanA_kernel(const int* __restrict__ cnt,
                             int* __restrict__ seg_scan,
                             int* __restrict__ blockSums, int n) {
    __shared__ int tsum[SCAN_BS];
    int b = blockIdx.x, t = threadIdx.x;
    int base = b * SCAN_CHUNK + t * SCAN_ELEMS;
    int vals[SCAN_ELEMS];
    int s = 0;
#pragma unroll
    for (int j = 0; j < SCAN_ELEMS; j++) {
        vals[j] = (base + j < n) ? cnt[base + j] : 0;
        s += vals[j];
    }
    tsum[t] = s;
    __syncthreads();
    for (int off = 1; off < SCAN_BS; off <<= 1) {
        int x = (t >= off) ? tsum[t - off] : 0;
        __syncthreads();
        tsum[t] += x;
        __syncthreads();
    }
    int run = tsum[t] - s;  // exclusive prefix of this thread's chunk
#pragma unroll
    for (int j = 0; j < SCAN_ELEMS; j++) {
        if (base + j < n) seg_scan[base + j] = run;
        run += vals[j];
    }
    if (t == SCAN_BS - 1) blockSums[b] = tsum[t];
}

__global__ void scanB_kernel(const int* __restrict__ blockSums,
                             int* __restrict__ blockOffs, int nb) {
    __shared__ int sh[SCAN_BS];
    int t = threadIdx.x;
    int v = (t < nb) ? blockSums[t] : 0;
    sh[t] = v;
    __syncthreads();
    for (int off = 1; off < SCAN_BS; off <<= 1) {
        int x = (t >= off) ? sh[t - off] : 0;
        __syncthreads();
        sh[t] += x;
        __syncthreads();
    }
    if (t < nb) blockOffs[t] = sh[t] - v;  // exclusive
}

__global__ void scanC_kernel(const int* __restrict__ seg_scan,
                             const int* __restrict__ blockOffs,
                             int* __restrict__ seg_start,
                             int* __restrict__ cursor, int n, int total) {
    int i = blockIdx.x * blockDim.x + threadIdx.x;
    if (i < n) {
        int v = seg_scan[i] + blockOffs[i / SCAN_CHUNK];
        seg_start[i] = v;
        cursor[i] = v;
    }
    if (i == 0) seg_start[n] = total;
}

// ---------------------------------------------------------------------------
// bin: scatter each edge's SOURCE node id into its (dst,rating) CSR slot
// ---------------------------------------------------------------------------
__global__ void bin_kernel(const int* __restrict__ u_s,
                           const int* __restrict__ v_s,
                           const int* __restrict__ rate,
                           int* __restrict__ cursor,
                           int* __restrict__ sorted_src, int n_edges) {
    int e = blockIdx.x * blockDim.x + threadIdx.x;
    if (e >= n_edges) return;
    int u = u_s[e], v = v_s[e], r = rate[e];
    int pu = atomicAdd(&cursor[u * RATES + r], 1);
    sorted_src[pu] = v;
    int pv = atomicAdd(&cursor[SEG_U + v * RATES + r], 1);
    sorted_src[pv] = u;
}

// ---------------------------------------------------------------------------
// fused aggregate + matmul: one wave per T nodes.
// Phase 1: gather-sum each (node,rating) segment's source rows into LDS.
// Phase 2: out[n,h] = sum_r inv_c * sum_d sums[n,r,d]*W[r,d,h]  (lane = h)
// ---------------------------------------------------------------------------
constexpr int T = 8;        // nodes per wave
constexpr int WPB = 4;      // waves per 256-thread block

__global__ __launch_bounds__(256) void aggmm_kernel(
        const int* __restrict__ sorted_src,
        const int* __restrict__ seg_start,   // combined scan, seg_base offsets in
        const float* __restrict__ x_src,
        const float* __restrict__ W,         // [RATES][F][F]
        float* __restrict__ out,
        int n_nodes, int seg_base) {
    __shared__ float sums[WPB][T][RATES][F];    // 4*8*5*64*4 = 40 KB
    __shared__ float invc[WPB][T][RATES];       // 640 B

    int wid  = threadIdx.x >> 6;
    int lane = threadIdx.x & 63;
    int wave = (int)(((long)blockIdx.x * blockDim.x + threadIdx.x) >> 6);
    int node0 = wave * T;
    if (node0 >= n_nodes) return;

    // Phase 1: segment gather-sums (seg_start reads are wave-uniform scalars;
    // x row reads are 256B coalesced; LLC-resident tables).
    for (int t = 0; t < T; t++) {
        int node = node0 + t;
        for (int r = 0; r < RATES; r++) {
            int seg = seg_base + node * RATES + r;
            int s  = seg_start[seg];
            int e2 = seg_start[seg + 1];
            float acc0 = 0.f, acc1 = 0.f;
            int e = s;
            for (; e + 1 < e2; e += 2) {   // 2-way unroll to break latency chain
                int s0 = sorted_src[e];
                int s1 = sorted_src[e + 1];
                acc0 += x_src[(long)s0 * F + lane];
                acc1 += x_src[(long)s1 * F + lane];
            }
            if (e < e2) acc0 += x_src[(long)sorted_src[e] * F + lane];
            sums[wid][t][r][lane] = acc0 + acc1;
            if (lane == 0)
                invc[wid][t][r] = 1.0f / fmaxf((float)(e2 - s), 1.0f);
        }
    }
    // Wave-private LDS region: no __syncthreads needed; compiler inserts
    // lgkmcnt waits between ds_write and ds_read within the wave.
    __builtin_amdgcn_s_waitcnt(0);  // belt-and-suspenders: drain lgkm+vm

    // Phase 2: matmul. W loads coalesced in lane; sums/invc reads are LDS
    // broadcasts (uniform address -> no bank conflict).
    float acc[T];
#pragma unroll
    for (int t = 0; t < T; t++) acc[t] = 0.f;

    for (int r = 0; r < RATES; r++) {
        float partial[T];
#pragma unroll
        for (int t = 0; t < T; t++) partial[t] = 0.f;

        for (int d0 = 0; d0 < F; d0 += 8) {
            float w[8];
#pragma unroll
            for (int j = 0; j < 8; j++)
                w[j] = W[((long)r * F + d0 + j) * F + lane];
#pragma unroll
            for (int t = 0; t < T; t++) {
#pragma unroll
                for (int j = 0; j < 8; j++)
                    partial[t] += sums[wid][t][r][d0 + j] * w[j];
            }
        }
#pragma unroll
        for (int t = 0; t < T; t++)
            acc[t] += partial[t] * invc[wid][t][r];
    }
#pragma unroll
    for (int t = 0; t < T; t++)
        out[(long)(node0 + t) * F + lane] = acc[t];
}

// ---------------------------------------------------------------------------
extern "C" void kernel_launch(void* const* d_in, const int* in_sizes, int n_in,
                              void* d_out, int out_size, void* d_ws, size_t ws_size,
                              hipStream_t stream) {
    const int*   u_s    = (const int*)d_in[0];
    const int*   v_s    = (const int*)d_in[1];
    const int*   rate   = (const int*)d_in[2];
    const float* x_user = (const float*)d_in[3];
    const float* x_item = (const float*)d_in[4];
    const float* W      = (const float*)d_in[5];
    float* out = (float*)d_out;

    int n_edges = in_sizes[0];
    long total_slots = 2L * n_edges;

    // Workspace layout (ints).
    int* cnt        = (int*)d_ws;                   // NS_TOTAL
    int* seg_scan   = cnt + NS_TOTAL;               // NS_TOTAL
    int* seg_start  = seg_scan + NS_TOTAL;          // NS_TOTAL + 1
    int* cursor     = seg_start + NS_TOTAL + 1;     // NS_TOTAL
    int* blockSums  = cursor + NS_TOTAL;            // SCAN_NB
    int* blockOffs  = blockSums + SCAN_NB;          // SCAN_NB
    int* sorted_src = blockOffs + SCAN_NB;          // 2*n_edges
    size_t need = (size_t)((sorted_src - cnt) + total_slots) * sizeof(int);
    if (need > ws_size) {
        // Workspace too small: zero output only (visible failure, no OOB).
        zero_ints<<<2048, 256, 0, stream>>>((int*)out, OUT_FLOATS);
        return;
    }

    // 1) zero counts
    zero_ints<<<(NS_TOTAL + 256 * 8 - 1) / (256 * 8), 256, 0, stream>>>(cnt, NS_TOTAL);

    // 2) histogram
    int eb = (n_edges + 255) / 256;
    hist_kernel<<<eb, 256, 0, stream>>>(u_s, v_s, rate, cnt, n_edges);

    // 3) scan
    scanA_kernel<<<SCAN_NB, SCAN_BS, 0, stream>>>(cnt, seg_scan, blockSums, NS_TOTAL);
    scanB_kernel<<<1, SCAN_BS, 0, stream>>>(blockSums, blockOffs, SCAN_NB);
    scanC_kernel<<<(NS_TOTAL + 255) / 256, 256, 0, stream>>>(
        seg_scan, blockOffs, seg_start, cursor, NS_TOTAL, (int)total_slots);

    // 4) bin edges into CSR
    bin_kernel<<<eb, 256, 0, stream>>>(u_s, v_s, rate, cursor, sorted_src, n_edges);

    // 5) fused aggregate+matmul, both directions
    {
        float* h_u = out;
        float* h_v = out + (long)N_USERS * F;
        int waves_u  = N_USERS / T;                       // 6250
        int blocks_u = (waves_u + WPB - 1) / WPB;         // 1563
        aggmm_kernel<<<blocks_u, 256, 0, stream>>>(
            sorted_src, seg_start, x_item, W, h_u, N_USERS, 0);
        int waves_v  = N_ITEMS / T;                       // 2500
        int blocks_v = (waves_v + WPB - 1) / WPB;         // 625
        aggmm_kernel<<<blocks_v, 256, 0, stream>>>(
            sorted_src, seg_start, x_user, W, h_v, N_ITEMS, SEG_U);
    }
}